// Round 1
// 284.878 us; speedup vs baseline: 1.0487x; 1.0487x over previous
//
#include <hip/hip_runtime.h>
#include <hip/hip_bf16.h>
#include <math.h>

// EdgeDistancesPassing: out[e] = exp(-relu(relu((f[src]-f[dst])@W1 + b1)@W2 + b2)) * f[dst]
// Linearity: (f[src]-f[dst])@W1 = P[src]-P[dst] with P = features@W1 (b1 added per-edge).
// T[node] = [P bf16 x64 | F bf16 x64] = 256 B/row (bf16-packed gather table).
// R5: edge kernel moves from 16 lanes/edge (8 B loads) to 8 lanes/edge (16 B loads):
//     same cache lines, half the VMEM instructions, half the waves, 3 shfl steps.

#define D 64
#define NPB 64   // nodes per block in projection kernel

typedef float nfloat4 __attribute__((ext_vector_type(4)));      // native vec for nontemporal builtin
typedef unsigned short ushort8v __attribute__((ext_vector_type(8)));

// round-to-nearest-even fp32 -> bf16 bits (inputs are finite)
static __device__ __forceinline__ unsigned short f2bf(float f) {
    unsigned u = __float_as_uint(f);
    u += 0x7fffu + ((u >> 16) & 1u);
    return (unsigned short)(u >> 16);
}
static __device__ __forceinline__ float bf2f(unsigned short b) {
    return __uint_as_float(((unsigned)b) << 16);
}

// ---------------- Kernel 1: build T = [bf16(F@W1) | bf16(F)] ----------------
__global__ __launch_bounds__(256) void node_proj_kernel(
    const float* __restrict__ F, const float* __restrict__ W1,
    ushort4* __restrict__ T, int n_nodes)   // T: [node][32] ushort4 (256 B/row)
{
    __shared__ float4 sW4[D * 16];    // [k][col4], 16 KB
    __shared__ float4 sF4[NPB * 16];  // [node][k4], 16 KB

    const int tid = threadIdx.x;
    const int base = blockIdx.x * NPB;
    const int nrows = min(NPB, n_nodes - base);

    // Stage W1 (coalesced)
    const float4* W4 = (const float4*)W1;
#pragma unroll
    for (int i = 0; i < 4; ++i) sW4[tid + i * 256] = W4[tid + i * 256];

    // Stage feature rows (coalesced)
    const float4* Fg = (const float4*)(F + (long)base * D);
    const int totalf4 = nrows * 16;
    for (int i = tid; i < totalf4; i += 256) sF4[i] = Fg[i];
    __syncthreads();

    const int tx = tid & 15;   // col group (cols 4tx..4tx+3)
    const int ty = tid >> 4;   // node group (nodes 4ty..4ty+3)

    float4 acc[4];
#pragma unroll
    for (int i = 0; i < 4; ++i) { acc[i].x = 0.f; acc[i].y = 0.f; acc[i].z = 0.f; acc[i].w = 0.f; }

#pragma unroll
    for (int k4 = 0; k4 < 16; ++k4) {
        float4 wr[4], fr[4];
#pragma unroll
        for (int r = 0; r < 4; ++r) wr[r] = sW4[(k4 * 4 + r) * 16 + tx];
#pragma unroll
        for (int i = 0; i < 4; ++i) fr[i] = sF4[(ty * 4 + i) * 16 + k4];
#pragma unroll
        for (int i = 0; i < 4; ++i) {
            acc[i].x += fr[i].x * wr[0].x + fr[i].y * wr[1].x + fr[i].z * wr[2].x + fr[i].w * wr[3].x;
            acc[i].y += fr[i].x * wr[0].y + fr[i].y * wr[1].y + fr[i].z * wr[2].y + fr[i].w * wr[3].y;
            acc[i].z += fr[i].x * wr[0].z + fr[i].y * wr[1].z + fr[i].z * wr[2].z + fr[i].w * wr[3].z;
            acc[i].w += fr[i].x * wr[0].w + fr[i].y * wr[1].w + fr[i].z * wr[2].w + fr[i].w * wr[3].w;
        }
    }

    // Write P half (bf16): row slot tx covers cols 4tx..4tx+3
#pragma unroll
    for (int i = 0; i < 4; ++i) {
        const int n = ty * 4 + i;
        if (n < nrows) {
            ushort4 pu;
            pu.x = f2bf(acc[i].x); pu.y = f2bf(acc[i].y);
            pu.z = f2bf(acc[i].z); pu.w = f2bf(acc[i].w);
            T[(long)(base + n) * 32 + tx] = pu;
        }
    }

    // Write F half (bf16) from staged sF4: 1024 chunks / 256 threads
#pragma unroll
    for (int c = tid; c < NPB * 16; c += 256) {
        const int n = c >> 4;
        if (n < nrows) {
            const int sub = c & 15;
            const float4 f = sF4[c];
            ushort4 fu;
            fu.x = f2bf(f.x); fu.y = f2bf(f.y); fu.z = f2bf(f.z); fu.w = f2bf(f.w);
            T[(long)(base + n) * 32 + 16 + sub] = fu;
        }
    }
}

// ---------------- Kernel 2: per-edge fused epilogue (8 lanes/edge, 16 B loads) ----------------
__global__ __launch_bounds__(256) void edge_kernel(
    const ushort8v* __restrict__ T8,   // T viewed as rows of 16 x ushort8 (256 B/row)
    const int* __restrict__ src_idx, const int* __restrict__ dst_idx,
    const float* __restrict__ b1, const float* __restrict__ W2,
    const float* __restrict__ b2v,
    float* __restrict__ out, int n_edges)
{
    const int tid = blockIdx.x * blockDim.x + threadIdx.x;
    const int lane8 = threadIdx.x & 7;   // covers cols 8*lane8 .. 8*lane8+7
    const int e = tid >> 3;
    if (e >= n_edges) return;

    // Per-lane slices of b1 and W2 (8 consecutive floats each)
    const float4 b1a = ((const float4*)b1)[lane8 * 2];
    const float4 b1b = ((const float4*)b1)[lane8 * 2 + 1];
    const float4 w2a = ((const float4*)W2)[lane8 * 2];
    const float4 w2b = ((const float4*)W2)[lane8 * 2 + 1];
    const float b2s = b2v[0];

    const long s = (long)src_idx[e];
    const long d = (long)dst_idx[e];

    // 3 x 16 B gathers per lane: P[src], P[dst], F[dst] (each row-gather = one 128 B line)
    const ushort8v psu = T8[s * 16 + lane8];
    const ushort8v pdu = T8[d * 16 + lane8];
    const ushort8v fdu = T8[d * 16 + 8 + lane8];

    float b1r[8] = {b1a.x, b1a.y, b1a.z, b1a.w, b1b.x, b1b.y, b1b.z, b1b.w};
    float w2r[8] = {w2a.x, w2a.y, w2a.z, w2a.w, w2b.x, w2b.y, w2b.z, w2b.w};

    float dot = 0.f;
#pragma unroll
    for (int j = 0; j < 8; ++j) {
        const float h = fmaxf(bf2f(psu[j]) - bf2f(pdu[j]) + b1r[j], 0.f);
        dot += h * w2r[j];
    }
    dot += __shfl_xor(dot, 1);
    dot += __shfl_xor(dot, 2);
    dot += __shfl_xor(dot, 4);

    const float a = __expf(-fmaxf(dot + b2s, 0.f));

    nfloat4 oa, ob;
    oa.x = a * bf2f(fdu[0]); oa.y = a * bf2f(fdu[1]);
    oa.z = a * bf2f(fdu[2]); oa.w = a * bf2f(fdu[3]);
    ob.x = a * bf2f(fdu[4]); ob.y = a * bf2f(fdu[5]);
    ob.z = a * bf2f(fdu[6]); ob.w = a * bf2f(fdu[7]);
    nfloat4* dst4 = (nfloat4*)(out + (long)e * D + lane8 * 8);
    __builtin_nontemporal_store(oa, dst4);
    __builtin_nontemporal_store(ob, dst4 + 1);
}

extern "C" void kernel_launch(void* const* d_in, const int* in_sizes, int n_in,
                              void* d_out, int out_size, void* d_ws, size_t ws_size,
                              hipStream_t stream) {
    const float* features = (const float*)d_in[0];
    const int*   src_idx  = (const int*)d_in[1];
    const int*   dst_idx  = (const int*)d_in[2];
    const float* W1       = (const float*)d_in[3];
    const float* b1       = (const float*)d_in[4];
    const float* W2       = (const float*)d_in[5];
    const float* b2       = (const float*)d_in[6];
    float* out = (float*)d_out;

    const int n_nodes = in_sizes[0] / D;
    const int n_edges = in_sizes[1];

    ushort4* T = (ushort4*)d_ws;  // n_nodes * 256 B = 12.8 MB

    const int grid1 = (n_nodes + NPB - 1) / NPB;
    node_proj_kernel<<<grid1, 256, 0, stream>>>(features, W1, T, n_nodes);

    const int edges_per_block = 256 / 8;  // 32 edges per block
    const int grid2 = (n_edges + edges_per_block - 1) / edges_per_block;
    edge_kernel<<<grid2, 256, 0, stream>>>((const ushort8v*)T, src_idx, dst_idx,
                                           b1, W2, b2, out, n_edges);
}